// Round 10
// baseline (64.972 us; speedup 1.0000x reference)
//
#include <hip/hip_runtime.h>

// MHAGRU, 2 kernels: [single-wave fused inproj+GRU+MHA per 2 features] -> [out_proj].
// B=32 T=64 F=128 H=8 NH=4 HD=2 HID=32. All f32.
// d_out = [ y (B*T*HID) | attention (B*T*F*H) ]
// d_ws  = [ out (B*F,T,H) ] (written by K1, read by K2)
//
// R10: barrier-free wave-programs. 2048 blocks x 64 threads; each wave owns
// (b, 2 f's): A inproj (x from global/L2, Wp scalar) -> B GRU (lanes 0-15) ->
// h burst-store -> C MHA (component-split kv, row-owner q/ctx overlay) ->
// attn burst store. Zero __syncthreads; all ordering is within-wave lgkmcnt.
// Waves at different phases co-schedule -> no convoy.

namespace {
constexpr int Bb = 32, Tt = 64, Ff = 128, Hh = 8, HIDh = 32;
constexpr int G3H = 24;
constexpr float L2E = 1.44269504088896340736f;
// LDS (floats): XPS [2][65] | UB [2][772] (h/q/ctx/o8, row stride 12) | KV 4x[4][68]
constexpr int XPS = 0;
constexpr int UB  = 132;                  // 16B aligned (132*4=528)
constexpr int UBS = 772;                  // per-f stride (772*4 % 16 == 0)
constexpr int KV  = 132 + 2 * 772;        // 1676 (1676*4 % 16 == 0)
constexpr int KK0 = KV, KK1 = KV + 272, VV0 = KV + 544, VV1 = KV + 816;
constexpr int SM_SIZE = KV + 1088;        // 2764 floats = 11.1 KB -> 8+ blocks/CU
}

__device__ __forceinline__ float rcp_(float x) {
#if __has_builtin(__builtin_amdgcn_rcpf)
  return __builtin_amdgcn_rcpf(x);
#else
  return 1.0f / x;
#endif
}
__device__ __forceinline__ float exp2_(float x) {
#if __has_builtin(__builtin_amdgcn_exp2f)
  return __builtin_amdgcn_exp2f(x);
#else
  return exp2f(x);
#endif
}

// 4-row softmax+PV step per kv component (R6/R8 proven)
#define MHA_STEP(K0C, K1C, V0C, V1C)                         \
  {                                                          \
    _Pragma("unroll") for (int i = 0; i < 4; ++i) {          \
      float s = fmaf(q0[i], K0C, q1[i] * K1C);               \
      float p = exp2_(s);                                    \
      ps[i] += p;                                            \
      c0[i] = fmaf(p, V0C, c0[i]);                           \
      c1[i] = fmaf(p, V1C, c1[i]);                           \
    }                                                        \
  }

// ---------------- K1: one wave per (b, 2f); A -> B -> C, barrier-free ----------------
// grid: B * F/2 = 2048 blocks, 64 threads.
__global__ __launch_bounds__(64) void k_fused(
    const float* __restrict__ x, const float* __restrict__ Wp, const float* __restrict__ bp,
    const float* __restrict__ W_ih, const float* __restrict__ b_ih,
    const float* __restrict__ W_hh, const float* __restrict__ b_hh,
    const float* __restrict__ in_w, const float* __restrict__ in_b,
    const float* __restrict__ ow, const float* __restrict__ ob,
    float* __restrict__ outp, float* __restrict__ attn) {
  __shared__ float smem[SM_SIZE];
  const int t = threadIdx.x;          // lane = time row
  const int blk = blockIdx.x;
  const int b = blk >> 6;
  const int f0 = (blk & 63) * 2;

  // ---- phase A: xp[t][2f] = x[b,t,:] . Wp[f,:] + bp (x coalesced, Wp scalar) ----
  {
    const float4* xr = (const float4*)(x + (b * Tt + t) * Ff);
    const float4* wA = (const float4*)(Wp + f0 * Ff);
    const float4* wB = (const float4*)(Wp + (f0 + 1) * Ff);
    float a0 = bp[f0], a1 = bp[f0 + 1];
#pragma unroll 8
    for (int k = 0; k < Ff / 4; ++k) {
      float4 xv = xr[k], va = wA[k], vb = wB[k];
      a0 = fmaf(xv.x, va.x, a0); a0 = fmaf(xv.y, va.y, a0);
      a0 = fmaf(xv.z, va.z, a0); a0 = fmaf(xv.w, va.w, a0);
      a1 = fmaf(xv.x, vb.x, a1); a1 = fmaf(xv.y, vb.y, a1);
      a1 = fmaf(xv.z, vb.z, a1); a1 = fmaf(xv.w, vb.w, a1);
    }
    smem[XPS + t] = a0;
    smem[XPS + 65 + t] = a1;
  }
  asm volatile("s_waitcnt lgkmcnt(0)" ::: "memory");   // xp visible within wave

  // ---- phase B: GRU scan, lanes 0..15 (g=f_local, j=hidden); h -> UB rows ----
  if (t < 16) {
    __builtin_amdgcn_s_setprio(1);
    const int g = t >> 3, j = t & 7;
    const int f = f0 + g;
    const float* wb = W_hh + (f * G3H + j) * Hh;
    const float nL = -L2E, S2 = 2.0f * L2E;
    float w0s[8], w1s[8], w2s[8];
#pragma unroll
    for (int h = 0; h < 8; ++h) {
      w0s[h] = wb[h] * nL;
      w1s[h] = wb[64 + h] * nL;
      w2s[h] = wb[128 + h] * S2;
    }
    const float wi0s = W_ih[f * G3H + j] * nL;
    const float wi1s = W_ih[f * G3H + 8 + j] * nL;
    const float wi2s = W_ih[f * G3H + 16 + j] * S2;
    const float bias_r = (b_ih[f * G3H + j] + b_hh[f * G3H + j]) * nL;
    const float bias_z = (b_ih[f * G3H + 8 + j] + b_hh[f * G3H + 8 + j]) * nL;
    const float bi2s = b_ih[f * G3H + 16 + j] * S2;
    const float bh2s = b_hh[f * G3H + 16 + j] * S2;
    float hall[8];
#pragma unroll
    for (int h = 0; h < 8; ++h) hall[h] = 0.f;
    float h_own = 0.f;                      // == hall[j], avoids dynamic index
    const int base = t & 56;                // {0, 8}
    float* hdst = &smem[UB + g * UBS + j];
    const float* xps = &smem[XPS + g * 65];
    for (int tt = 0; tt < Tt; ++tt) {
      float xt = xps[tt];
      float a0 = bias_r, a1 = bias_z, a2 = bh2s;
#pragma unroll
      for (int h = 0; h < 8; ++h) {
        a0 = fmaf(hall[h], w0s[h], a0);
        a1 = fmaf(hall[h], w1s[h], a1);
        a2 = fmaf(hall[h], w2s[h], a2);
      }
      float r = rcp_(1.0f + exp2_(fmaf(xt, wi0s, a0)));
      float z = rcp_(1.0f + exp2_(fmaf(xt, wi1s, a1)));
      float narg = fmaf(r, a2, fmaf(xt, wi2s, bi2s));
      float n = fmaf(-2.0f, rcp_(exp2_(narg) + 1.0f), 1.0f);  // tanh
      float hn = fmaf(z, h_own - n, n);
      hdst[tt * 12] = hn;
      h_own = hn;
#pragma unroll
      for (int h = 0; h < 8; ++h) hall[h] = __shfl(hn, base + h, 64);
    }
    __builtin_amdgcn_s_setprio(0);
  }
  asm volatile("s_waitcnt lgkmcnt(0)" ::: "memory");   // h visible within wave

  // ---- burst h -> outp (for out_proj): 2f x 64t x 8h, 2KB contiguous per f ----
  {
    float4* og = (float4*)(outp + (b * Ff + f0) * Tt * Hh);
#pragma unroll
    for (int i = 0; i < 4; ++i) {
      int v = i * 64 + t;                 // float4 index (256 total)
      int fl = v >> 7, rem = v & 127;
      int tt = rem >> 1, j0 = (rem & 1) * 4;
      og[v] = *(const float4*)&smem[UB + fl * UBS + tt * 12 + j0];
    }
  }
  asm volatile("s_waitcnt lgkmcnt(0)" ::: "memory");   // h reads done before q overwrite

  // ---- phase C: MHA per f (sequential over the wave's 2 f's) ----
  constexpr float SCL = 0.70710678118654752f * L2E;
#pragma unroll
  for (int fl = 0; fl < 2; ++fl) {
    float* ub = &smem[UB + fl * UBS];
    // C1: lane t = row t. Read h, project qkv, write q back to own row, kv split.
    float sq[8];
    *(float4*)&sq[0] = *(const float4*)&ub[t * 12];
    *(float4*)&sq[4] = *(const float4*)&ub[t * 12 + 4];
    float qv[8], ka[8], va[8];
#pragma unroll
    for (int jj = 0; jj < 8; ++jj) {
      float aq = in_b[jj], ak = in_b[8 + jj], av = in_b[16 + jj];
#pragma unroll
      for (int h = 0; h < 8; ++h) {
        aq = fmaf(sq[h], in_w[jj * 8 + h], aq);
        ak = fmaf(sq[h], in_w[(8 + jj) * 8 + h], ak);
        av = fmaf(sq[h], in_w[(16 + jj) * 8 + h], av);
      }
      qv[jj] = aq * SCL; ka[jj] = ak; va[jj] = av;
    }
    *(float4*)&ub[t * 12] = make_float4(qv[0], qv[1], qv[2], qv[3]);
    *(float4*)&ub[t * 12 + 4] = make_float4(qv[4], qv[5], qv[6], qv[7]);
#pragma unroll
    for (int n = 0; n < 4; ++n) {
      smem[KK0 + n * 68 + t] = ka[2 * n];
      smem[KK1 + n * 68 + t] = ka[2 * n + 1];
      smem[VV0 + n * 68 + t] = va[2 * n];
      smem[VV1 + n * 68 + t] = va[2 * n + 1];
    }
    asm volatile("s_waitcnt lgkmcnt(0)" ::: "memory");

    // C2: lane = (n = t>>4, qq = t&15); 4 q-rows x 1 head; kv b128 broadcast chunks
    {
      const int n = t >> 4, qq = t & 15;
      float q0[4], q1[4];
#pragma unroll
      for (int i = 0; i < 4; ++i) {
        float2 qp = *(const float2*)&ub[(qq + 16 * i) * 12 + 2 * n];
        q0[i] = qp.x; q1[i] = qp.y;
      }
      float ps[4], c0[4], c1[4];
#pragma unroll
      for (int i = 0; i < 4; ++i) { ps[i] = 0.f; c0[i] = 0.f; c1[i] = 0.f; }
#pragma unroll 2
      for (int kt4 = 0; kt4 < Tt; kt4 += 4) {
        float4 k0 = *(const float4*)&smem[KK0 + n * 68 + kt4];
        float4 k1 = *(const float4*)&smem[KK1 + n * 68 + kt4];
        float4 v0 = *(const float4*)&smem[VV0 + n * 68 + kt4];
        float4 v1 = *(const float4*)&smem[VV1 + n * 68 + kt4];
        MHA_STEP(k0.x, k1.x, v0.x, v1.x)
        MHA_STEP(k0.y, k1.y, v0.y, v1.y)
        MHA_STEP(k0.z, k1.z, v0.z, v1.z)
        MHA_STEP(k0.w, k1.w, v0.w, v1.w)
      }
#pragma unroll
      for (int i = 0; i < 4; ++i) {
        float inv = rcp_(ps[i]);
        *(float2*)&ub[(qq + 16 * i) * 12 + 2 * n] =
            make_float2(c0[i] * inv, c1[i] * inv);   // ctx over q
      }
    }
    asm volatile("s_waitcnt lgkmcnt(0)" ::: "memory");

    // C3: lane t: out_proj of ctx row t, o8 back into own row
    {
      float cx[8];
      *(float4*)&cx[0] = *(const float4*)&ub[t * 12];
      *(float4*)&cx[4] = *(const float4*)&ub[t * 12 + 4];
      float o8[8];
#pragma unroll
      for (int jj = 0; jj < 8; ++jj) {
        float a = ob[jj];
#pragma unroll
        for (int h = 0; h < 8; ++h) a = fmaf(cx[h], ow[jj * 8 + h], a);
        o8[jj] = a;
      }
      *(float4*)&ub[t * 12] = make_float4(o8[0], o8[1], o8[2], o8[3]);
      *(float4*)&ub[t * 12 + 4] = make_float4(o8[4], o8[5], o8[6], o8[7]);
    }
    asm volatile("s_waitcnt lgkmcnt(0)" ::: "memory");
  }

  // ---- attn burst store: per t, 2f x 8h = 64B contiguous ----
  {
#pragma unroll
    for (int i = 0; i < 4; ++i) {
      int v = i * 64 + t;                  // float4 index (256 total)
      int tt = v >> 2, c = v & 3;
      int fl = c >> 1, h0 = (c & 1) * 4;
      float4 val = *(const float4*)&smem[UB + fl * UBS + tt * 12 + h0];
      *(float4*)(attn + ((b * Tt + tt) * Ff + f0 + fl) * Hh + h0) = val;
    }
  }
}

// ---------------- K2: y = out.reshape(B,T,F*H) @ Wout^T + bout ----------------
// grid: B*(T/8) = 256 blocks, 128 threads = 8 o-quads x 16 f-chunks (R2 proven).
__global__ __launch_bounds__(128) void k_outproj(
    const float* __restrict__ outp, const float* __restrict__ Wout,
    const float* __restrict__ bout, float* __restrict__ y) {
  constexpr int TT = 8;
  int blk = blockIdx.x;
  int b = blk >> 3;
  int t0 = (blk & 7) * TT;
  int tid = threadIdx.x;
  int oq = tid >> 4;
  int fc = tid & 15;
  float acc[TT][4];
#pragma unroll
  for (int tt = 0; tt < TT; ++tt)
#pragma unroll
    for (int od = 0; od < 4; ++od) acc[tt][od] = 0.f;
#pragma unroll
  for (int ff = 0; ff < 8; ++ff) {
    int f = fc * 8 + ff;
    const float4* rb = (const float4*)(outp + ((b * Ff + f) * Tt + t0) * Hh);
    float4 rv[16];
#pragma unroll
    for (int i = 0; i < 16; ++i) rv[i] = rb[i];
#pragma unroll
    for (int od = 0; od < 4; ++od) {
      int o = oq * 4 + od;
      const float4* wbp = (const float4*)(Wout + o * (Ff * Hh) + f * Hh);
      float4 wa = wbp[0], wc = wbp[1];
#pragma unroll
      for (int tt = 0; tt < TT; ++tt) {
        float4 ra = rv[tt * 2], rc = rv[tt * 2 + 1];
        float s = acc[tt][od];
        s = fmaf(ra.x, wa.x, s); s = fmaf(ra.y, wa.y, s);
        s = fmaf(ra.z, wa.z, s); s = fmaf(ra.w, wa.w, s);
        s = fmaf(rc.x, wc.x, s); s = fmaf(rc.y, wc.y, s);
        s = fmaf(rc.z, wc.z, s); s = fmaf(rc.w, wc.w, s);
        acc[tt][od] = s;
      }
    }
  }
#pragma unroll
  for (int tt = 0; tt < TT; ++tt)
#pragma unroll
    for (int od = 0; od < 4; ++od) {
      float v = acc[tt][od];
      v += __shfl_xor(v, 1, 16);
      v += __shfl_xor(v, 2, 16);
      v += __shfl_xor(v, 4, 16);
      v += __shfl_xor(v, 8, 16);
      acc[tt][od] = v;
    }
#pragma unroll
  for (int tt = 0; tt < TT; ++tt) {
    if (fc == tt) {
#pragma unroll
      for (int od = 0; od < 4; ++od) {
        int o = oq * 4 + od;
        y[(b * Tt + t0 + tt) * HIDh + o] = acc[tt][od] + bout[o];
      }
    }
  }
}

extern "C" void kernel_launch(void* const* d_in, const int* in_sizes, int n_in,
                              void* d_out, int out_size, void* d_ws, size_t ws_size,
                              hipStream_t stream) {
  (void)in_sizes; (void)n_in; (void)out_size; (void)ws_size;
  const float* x    = (const float*)d_in[0];
  const float* Wp   = (const float*)d_in[1];
  const float* bp   = (const float*)d_in[2];
  const float* W_ih = (const float*)d_in[3];
  const float* b_ih = (const float*)d_in[4];
  const float* W_hh = (const float*)d_in[5];
  const float* b_hh = (const float*)d_in[6];
  const float* in_w = (const float*)d_in[7];
  const float* in_b = (const float*)d_in[8];
  const float* ow   = (const float*)d_in[9];
  const float* ob   = (const float*)d_in[10];
  const float* Wout = (const float*)d_in[11];
  const float* bout = (const float*)d_in[12];

  float* y    = (float*)d_out;
  float* attn = (float*)d_out + Bb * Tt * HIDh;
  float* outp = (float*)d_ws;   // B*F*T*H

  hipLaunchKernelGGL(k_fused, dim3(Bb * (Ff / 2)), dim3(64), 0, stream,
                     x, Wp, bp, W_ih, b_ih, W_hh, b_hh, in_w, in_b, ow, ob, outp, attn);
  hipLaunchKernelGGL(k_outproj, dim3(Bb * (Tt / 8)), dim3(128), 0, stream,
                     outp, Wout, bout, y);
}

// Round 11
// 61.926 us; speedup vs baseline: 1.0492x; 1.0492x over previous
//
#include <hip/hip_runtime.h>

// MHAGRU, 2 kernels: [inproj+GRU+MHA fused, 4f/block, 37KB LDS -> 4 blocks/CU] -> [out_proj].
// B=32 T=64 F=128 H=8 NH=4 HD=2 HID=32. All f32.
// d_out = [ y (B*T*HID) | attention (B*T*F*H) ]
// d_ws  = [ out (B*F,T,H) ] (written by K1, read by K2)
//
// R11: occupancy release. R9's phase bodies verbatim, but block = (b, 4f),
// 1024 blocks x 4 waves; no x LDS tile (global/L1 reads); LDS 37KB ->
// 4 blocks/CU = 4 waves/SIMD (was 2). Theory: wall = VALU-issue / duty;
// duty was capped by 2 waves/SIMD latency hiding.

namespace {
constexpr int Bb = 32, Tt = 64, Ff = 128, Hh = 8, HIDh = 32;
constexpr int G3H = 24;
constexpr float L2E = 1.44269504088896340736f;
// LDS (floats), all regions disjoint:
constexpr int XPS  = 0;                    // xp [4 f][65 t]
constexpr int HOUT = 260;                  // h  [4 f][8 j][65 t]
constexpr int OCT  = 2340;                 // q/ctx/o8 [4 f][64 t][10]
constexpr int KV   = 4900;                 // per wave: kk0|kk1|vv0|vv1 [4][68]
constexpr int SM_SIZE = KV + 4 * 1088;     // 9252 floats = 37.0 KB
}

__device__ __forceinline__ float rcp_(float x) {
#if __has_builtin(__builtin_amdgcn_rcpf)
  return __builtin_amdgcn_rcpf(x);
#else
  return 1.0f / x;
#endif
}
__device__ __forceinline__ float exp2_(float x) {
#if __has_builtin(__builtin_amdgcn_exp2f)
  return __builtin_amdgcn_exp2f(x);
#else
  return exp2f(x);
#endif
}

// 4-row softmax+PV step per kv component (R6/R8/R9 proven)
#define MHA_STEP(K0C, K1C, V0C, V1C)                         \
  {                                                          \
    _Pragma("unroll") for (int i = 0; i < 4; ++i) {          \
      float s = fmaf(q0[i], K0C, q1[i] * K1C);               \
      float p = exp2_(s);                                    \
      ps[i] += p;                                            \
      c0[i] = fmaf(p, V0C, c0[i]);                           \
      c1[i] = fmaf(p, V1C, c1[i]);                           \
    }                                                        \
  }

// ---------------- K1: one block per (b, 4f); 256 threads = 4 waves ----------------
__global__ __launch_bounds__(256, 4) void k_fused(
    const float* __restrict__ x, const float* __restrict__ Wp, const float* __restrict__ bp,
    const float* __restrict__ W_ih, const float* __restrict__ b_ih,
    const float* __restrict__ W_hh, const float* __restrict__ b_hh,
    const float* __restrict__ in_w, const float* __restrict__ in_b,
    const float* __restrict__ ow, const float* __restrict__ ob,
    float* __restrict__ outp, float* __restrict__ attn) {
  __shared__ float smem[SM_SIZE];
  const int tid = threadIdx.x;
  const int t = tid & 63;
  const int w = tid >> 6;
  const int blk = blockIdx.x;
  const int b = blk >> 5;
  const int f0 = (blk & 31) * 4;

  // ---- phase A: wave w computes xp[:, f0+w]; x rows from global (L1/L2) ----
  {
    const int f = f0 + w;
    const float4* xr = (const float4*)(x + (b * Tt + t) * Ff);
    const float4* wr = (const float4*)(Wp + f * Ff);   // wave-uniform -> scalar
    float acc = bp[f];
#pragma unroll 8
    for (int k = 0; k < Ff / 4; ++k) {
      float4 xv = xr[k], wv = wr[k];
      acc = fmaf(xv.x, wv.x, acc); acc = fmaf(xv.y, wv.y, acc);
      acc = fmaf(xv.z, wv.z, acc); acc = fmaf(xv.w, wv.w, acc);
    }
    smem[XPS + w * 65 + t] = acc;
  }
  __syncthreads();

  // ---- phase B: GRU scan, wave 0 lanes 0..31 (g=f_local, j=hidden) ----
  if (tid < 32) {
    __builtin_amdgcn_s_setprio(1);
    const int g = t >> 3, j = t & 7;
    const int f = f0 + g;
    const float* wb = W_hh + (f * G3H + j) * Hh;
    const float nL = -L2E, S2 = 2.0f * L2E;
    float w0s[8], w1s[8], w2s[8];
#pragma unroll
    for (int h = 0; h < 8; ++h) {
      w0s[h] = wb[h] * nL;
      w1s[h] = wb[64 + h] * nL;
      w2s[h] = wb[128 + h] * S2;
    }
    const float wi0s = W_ih[f * G3H + j] * nL;
    const float wi1s = W_ih[f * G3H + 8 + j] * nL;
    const float wi2s = W_ih[f * G3H + 16 + j] * S2;
    const float bias_r = (b_ih[f * G3H + j] + b_hh[f * G3H + j]) * nL;
    const float bias_z = (b_ih[f * G3H + 8 + j] + b_hh[f * G3H + 8 + j]) * nL;
    const float bi2s = b_ih[f * G3H + 16 + j] * S2;
    const float bh2s = b_hh[f * G3H + 16 + j] * S2;
    float hall[8];
#pragma unroll
    for (int h = 0; h < 8; ++h) hall[h] = 0.f;
    float h_own = 0.f;                   // == hall[j] without dynamic index
    const int base = t & 56;             // 8-lane group base {0,8,16,24}
    float* hdst = &smem[HOUT + g * 520 + j * 65];   // banks 8g+j+tt: conflict-free
    const float* xps = &smem[XPS + g * 65];
    for (int tt = 0; tt < Tt; ++tt) {
      float xt = xps[tt];
      float a0 = bias_r, a1 = bias_z, a2 = bh2s;
#pragma unroll
      for (int h = 0; h < 8; ++h) {
        a0 = fmaf(hall[h], w0s[h], a0);
        a1 = fmaf(hall[h], w1s[h], a1);
        a2 = fmaf(hall[h], w2s[h], a2);
      }
      float r = rcp_(1.0f + exp2_(fmaf(xt, wi0s, a0)));
      float z = rcp_(1.0f + exp2_(fmaf(xt, wi1s, a1)));
      float narg = fmaf(r, a2, fmaf(xt, wi2s, bi2s));
      float n = fmaf(-2.0f, rcp_(exp2_(narg) + 1.0f), 1.0f);  // tanh
      float hn = fmaf(z, h_own - n, n);
      hdst[tt] = hn;
      h_own = hn;
#pragma unroll
      for (int h = 0; h < 8; ++h) hall[h] = __shfl(hn, base + h, 64);
    }
    __builtin_amdgcn_s_setprio(0);
  }
  __syncthreads();

  // ---- burst h -> outp: 4f x 64t x 8j = 8KB fully contiguous per block ----
  {
    float4* og = (float4*)(outp + (size_t)(b * Ff + f0) * Tt * Hh);
#pragma unroll
    for (int i = 0; i < 2; ++i) {
      int v = i * 256 + tid;             // float4 index (512 total)
      int fl = v >> 7, rem = v & 127;
      int tt = rem >> 1, j0 = (rem & 1) * 4;
      const float* hp = &smem[HOUT + fl * 520 + j0 * 65 + tt];
      og[v] = make_float4(hp[0], hp[65], hp[130], hp[195]);
    }
  }

  // ---- phase C: wave w handles f = f0 + w (one feature, wave-private) ----
  {
    constexpr float SCL = 0.70710678118654752f * L2E;
    const float* hsrc = &smem[HOUT + w * 520];
    float* oc = &smem[OCT + w * 640];
    float* kk0 = &smem[KV + w * 1088];
    float* kk1 = kk0 + 272;
    float* vv0 = kk0 + 544;
    float* vv1 = kk0 + 816;

    // C1: lane t = time row; qkv projection from LDS-resident h
    float sq[8];
#pragma unroll
    for (int h = 0; h < 8; ++h) sq[h] = hsrc[h * 65 + t];   // conflict-free
    float qv[8], ka[8], va[8];
#pragma unroll
    for (int jj = 0; jj < 8; ++jj) {
      float aq = in_b[jj], ak = in_b[8 + jj], av = in_b[16 + jj];
#pragma unroll
      for (int h = 0; h < 8; ++h) {
        aq = fmaf(sq[h], in_w[jj * 8 + h], aq);
        ak = fmaf(sq[h], in_w[(8 + jj) * 8 + h], ak);
        av = fmaf(sq[h], in_w[(16 + jj) * 8 + h], av);
      }
      qv[jj] = aq * SCL; ka[jj] = ak; va[jj] = av;
    }
#pragma unroll
    for (int n = 0; n < 4; ++n) {
      *(float2*)&oc[t * 10 + 2 * n] = make_float2(qv[2 * n], qv[2 * n + 1]);
      kk0[n * 68 + t] = ka[2 * n];
      kk1[n * 68 + t] = ka[2 * n + 1];
      vv0[n * 68 + t] = va[2 * n];
      vv1[n * 68 + t] = va[2 * n + 1];
    }
    asm volatile("s_waitcnt lgkmcnt(0)" ::: "memory");   // within-wave RAW

    // C2: lane = (n = t>>4, qq = t&15); 4 q-rows x 1 head; kv b128 broadcast
    const int n = t >> 4, qq = t & 15;
    float q0[4], q1[4];
#pragma unroll
    for (int i = 0; i < 4; ++i) {
      float2 qp = *(const float2*)&oc[(qq + 16 * i) * 10 + 2 * n];
      q0[i] = qp.x; q1[i] = qp.y;
    }
    float ps[4], c0[4], c1[4];
#pragma unroll
    for (int i = 0; i < 4; ++i) { ps[i] = 0.f; c0[i] = 0.f; c1[i] = 0.f; }
#pragma unroll 2
    for (int kt4 = 0; kt4 < Tt; kt4 += 4) {
      float4 k0 = *(const float4*)&kk0[n * 68 + kt4];
      float4 k1 = *(const float4*)&kk1[n * 68 + kt4];
      float4 v0 = *(const float4*)&vv0[n * 68 + kt4];
      float4 v1 = *(const float4*)&vv1[n * 68 + kt4];
      MHA_STEP(k0.x, k1.x, v0.x, v1.x)
      MHA_STEP(k0.y, k1.y, v0.y, v1.y)
      MHA_STEP(k0.z, k1.z, v0.z, v1.z)
      MHA_STEP(k0.w, k1.w, v0.w, v1.w)
    }
#pragma unroll
    for (int i = 0; i < 4; ++i) {
      float inv = rcp_(ps[i]);
      *(float2*)&oc[(qq + 16 * i) * 10 + 2 * n] =
          make_float2(c0[i] * inv, c1[i] * inv);   // ctx overwrites q
    }
    asm volatile("s_waitcnt lgkmcnt(0)" ::: "memory");

    // C3: lane t: out_proj of ctx row t, o8 back into own row
    {
      float2 cp0 = *(const float2*)&oc[t * 10 + 0];
      float2 cp1 = *(const float2*)&oc[t * 10 + 2];
      float2 cp2 = *(const float2*)&oc[t * 10 + 4];
      float2 cp3 = *(const float2*)&oc[t * 10 + 6];
      float cx[8] = {cp0.x, cp0.y, cp1.x, cp1.y, cp2.x, cp2.y, cp3.x, cp3.y};
      float o8[8];
#pragma unroll
      for (int jj = 0; jj < 8; ++jj) {
        float a = ob[jj];
#pragma unroll
        for (int h = 0; h < 8; ++h) a = fmaf(cx[h], ow[jj * 8 + h], a);
        o8[jj] = a;
      }
      *(float2*)&oc[t * 10 + 0] = make_float2(o8[0], o8[1]);
      *(float2*)&oc[t * 10 + 2] = make_float2(o8[2], o8[3]);
      *(float2*)&oc[t * 10 + 4] = make_float2(o8[4], o8[5]);
      *(float2*)&oc[t * 10 + 6] = make_float2(o8[6], o8[7]);
    }
  }
  __syncthreads();

  // ---- attn burst store: per t, 4f x 8h = 128B contiguous (full L2 lines) ----
  {
#pragma unroll
    for (int i = 0; i < 2; ++i) {
      int v = i * 256 + tid;              // float4 index (512 total)
      int tt = v >> 3, c = v & 7;
      int fl = c >> 1, h0 = (c & 1) * 4;
      const float* sp = &smem[OCT + fl * 640 + tt * 10 + h0];
      float4 val = make_float4(sp[0], sp[1], sp[2], sp[3]);
      *(float4*)(attn + (((size_t)b * Tt + tt) * Ff + f0 + fl) * Hh + h0) = val;
    }
  }
}

// ---------------- K2: y = out.reshape(B,T,F*H) @ Wout^T + bout ----------------
// grid: B*(T/8) = 256 blocks, 128 threads = 8 o-quads x 16 f-chunks (R2 proven).
__global__ __launch_bounds__(128) void k_outproj(
    const float* __restrict__ outp, const float* __restrict__ Wout,
    const float* __restrict__ bout, float* __restrict__ y) {
  constexpr int TT = 8;
  int blk = blockIdx.x;
  int b = blk >> 3;
  int t0 = (blk & 7) * TT;
  int tid = threadIdx.x;
  int oq = tid >> 4;
  int fc = tid & 15;
  float acc[TT][4];
#pragma unroll
  for (int tt = 0; tt < TT; ++tt)
#pragma unroll
    for (int od = 0; od < 4; ++od) acc[tt][od] = 0.f;
#pragma unroll
  for (int ff = 0; ff < 8; ++ff) {
    int f = fc * 8 + ff;
    const float4* rb = (const float4*)(outp + ((b * Ff + f) * Tt + t0) * Hh);
    float4 rv[16];
#pragma unroll
    for (int i = 0; i < 16; ++i) rv[i] = rb[i];
#pragma unroll
    for (int od = 0; od < 4; ++od) {
      int o = oq * 4 + od;
      const float4* wbp = (const float4*)(Wout + o * (Ff * Hh) + f * Hh);
      float4 wa = wbp[0], wc = wbp[1];
#pragma unroll
      for (int tt = 0; tt < TT; ++tt) {
        float4 ra = rv[tt * 2], rc = rv[tt * 2 + 1];
        float s = acc[tt][od];
        s = fmaf(ra.x, wa.x, s); s = fmaf(ra.y, wa.y, s);
        s = fmaf(ra.z, wa.z, s); s = fmaf(ra.w, wa.w, s);
        s = fmaf(rc.x, wc.x, s); s = fmaf(rc.y, wc.y, s);
        s = fmaf(rc.z, wc.z, s); s = fmaf(rc.w, wc.w, s);
        acc[tt][od] = s;
      }
    }
  }
#pragma unroll
  for (int tt = 0; tt < TT; ++tt)
#pragma unroll
    for (int od = 0; od < 4; ++od) {
      float v = acc[tt][od];
      v += __shfl_xor(v, 1, 16);
      v += __shfl_xor(v, 2, 16);
      v += __shfl_xor(v, 4, 16);
      v += __shfl_xor(v, 8, 16);
      acc[tt][od] = v;
    }
#pragma unroll
  for (int tt = 0; tt < TT; ++tt) {
    if (fc == tt) {
#pragma unroll
      for (int od = 0; od < 4; ++od) {
        int o = oq * 4 + od;
        y[(b * Tt + t0 + tt) * HIDh + o] = acc[tt][od] + bout[o];
      }
    }
  }
}

extern "C" void kernel_launch(void* const* d_in, const int* in_sizes, int n_in,
                              void* d_out, int out_size, void* d_ws, size_t ws_size,
                              hipStream_t stream) {
  (void)in_sizes; (void)n_in; (void)out_size; (void)ws_size;
  const float* x    = (const float*)d_in[0];
  const float* Wp   = (const float*)d_in[1];
  const float* bp   = (const float*)d_in[2];
  const float* W_ih = (const float*)d_in[3];
  const float* b_ih = (const float*)d_in[4];
  const float* W_hh = (const float*)d_in[5];
  const float* b_hh = (const float*)d_in[6];
  const float* in_w = (const float*)d_in[7];
  const float* in_b = (const float*)d_in[8];
  const float* ow   = (const float*)d_in[9];
  const float* ob   = (const float*)d_in[10];
  const float* Wout = (const float*)d_in[11];
  const float* bout = (const float*)d_in[12];

  float* y    = (float*)d_out;
  float* attn = (float*)d_out + Bb * Tt * HIDh;
  float* outp = (float*)d_ws;   // B*F*T*H

  hipLaunchKernelGGL(k_fused, dim3(Bb * (Ff / 4)), dim3(256), 0, stream,
                     x, Wp, bp, W_ih, b_ih, W_hh, b_hh, in_w, in_b, ow, ob, outp, attn);
  hipLaunchKernelGGL(k_outproj, dim3(Bb * (Tt / 8)), dim3(128), 0, stream,
                     outp, Wout, bout, y);
}